// Round 5
// baseline (158.304 us; speedup 1.0000x reference)
//
#include <hip/hip_runtime.h>
#include <stdint.h>

// Threefry-2x32, 20 rounds (Random123 / JAX threefry2x32_p).
__device__ __forceinline__ void tf2x32(uint32_t k0, uint32_t k1,
                                       uint32_t x0, uint32_t x1,
                                       uint32_t& o0, uint32_t& o1) {
  const uint32_t ks2 = k0 ^ k1 ^ 0x1BD11BDAu;
  x0 += k0; x1 += k1;
#define TF_R(r) { x0 += x1; x1 = __builtin_rotateleft32(x1, (r)); x1 ^= x0; }
  TF_R(13) TF_R(15) TF_R(26) TF_R(6)
  x0 += k1; x1 += ks2 + 1u;
  TF_R(17) TF_R(29) TF_R(16) TF_R(24)
  x0 += ks2; x1 += k0 + 2u;
  TF_R(13) TF_R(15) TF_R(26) TF_R(6)
  x0 += k0; x1 += k1 + 3u;
  TF_R(17) TF_R(29) TF_R(16) TF_R(24)
  x0 += k1; x1 += ks2 + 4u;
  TF_R(13) TF_R(15) TF_R(26) TF_R(6)
  x0 += ks2; x1 += k0 + 5u;
#undef TF_R
  o0 = x0; o1 = x1;
}

#define LCHUNK 50    // frames per chunk (p-refresh anchored at gi - gi%100)
#define F0     8     // unconditional both-chain warmup frames

// Kernel 0: per-frame schedule {ku0, ku1, thr32} -> uint4 table in ws.
// Writes nf+1 entries (entry nf is a pad for the main loop's prefetch).
// thr32 = ceil(p * 2^23) << 9 so that (uniform(u) < p) == (bits < thr32).
__global__ __launch_bounds__(256) void hmm_sched(
    const float* __restrict__ initial_trans,
    uint4* __restrict__ sched, int nf) {
  const int gi = blockIdx.x * blockDim.x + threadIdx.x;
  if (gi > nf) return;
  const float trans = initial_trans[0];
  uint32_t f0_, f1_, t0, t1;
  tf2x32(0u, 42u, 0u, (uint32_t)gi, f0_, f1_);        // fold_in(key(42), gi)
  tf2x32(f0_, f1_, 0u, 0u, t0, t1);                   // ku = split[0]
  const int jf = gi - (gi % 100);                     // p refresh anchor
  uint32_t g0, g1, kr0, kr1, a0, a1, b0, b1, h0, h1, l0, l1;
  tf2x32(0u, 42u, 0u, (uint32_t)jf, g0, g1);
  tf2x32(g0, g1, 0u, 1u, kr0, kr1);                   // kr = split[1]
  tf2x32(kr0, kr1, 0u, 0u, a0, a1);                   // randint: k1
  tf2x32(kr0, kr1, 0u, 1u, b0, b1);                   //          k2
  tf2x32(a0, a1, 0u, 0u, h0, h1);
  tf2x32(b0, b1, 0u, 0u, l0, l1);
  const uint32_t hb = h0 ^ h1, lb = l0 ^ l1;
  const uint32_t off = ((hb % 9u) * 4u + (lb % 9u)) % 9u;  // span 9, mult 4
  const float p = trans * (float)(1u + off);
  const uint32_t mant = (uint32_t)ceilf(p * 8388608.0f);
  sched[gi] = make_uint4(t0, t1, mant << 9, 0u);
}

// Both-chain update for one particle; returns 1 if chains still differ.
__device__ __forceinline__ uint32_t bothstep(uint32_t k0, uint32_t k1,
                                             uint32_t tp, uint32_t twon,
                                             uint32_t& sA, uint32_t& sB) {
  uint32_t a0, a1, b0, b1;
  tf2x32(k0, k1, 0u, twon, a0, a1);          // element for state 0
  tf2x32(k0, k1, 0u, twon + 1u, b0, b1);     // element for state 1
  const uint32_t flip0 = ((a0 ^ a1) < 0x80000000u) ? 1u : 0u;
  const uint32_t flip1 = ((b0 ^ b1) < tp) ? 1u : 0u;
  sA = sA ? (1u ^ flip1) : flip0;
  sB = sB ? (1u ^ flip1) : flip0;
  return (sA != sB) ? 1u : 0u;
}

// Merged single-chain update.
__device__ __forceinline__ void mstep(uint32_t k0, uint32_t k1, uint32_t tp,
                                      uint32_t twon, uint32_t& s) {
  uint32_t a0, a1;
  tf2x32(k0, k1, 0u, twon + s, a0, a1);
  const uint32_t thr = s ? tp : 0x80000000u;
  s ^= ((a0 ^ a1) < thr) ? 1u : 0u;
}

// Kernel 1: each thread owns FOUR particles (4t..4t+3) for one frame chunk.
// chunk 0 runs the true chain; chunks c>0 run both entry states until the
// chains couple (merge), then a single merged chain. float4 coalesced output.
__global__ __launch_bounds__(256) void hmm_main(
    const float* __restrict__ initial,
    const uint4* __restrict__ sched,
    float* __restrict__ out,
    uchar4* __restrict__ fin,
    int N, int nf) {
  const int t = blockIdx.x * blockDim.x + threadIdx.x;
  const int n0 = 4 * t;
  if (n0 >= N) return;
  const int c = blockIdx.y;
  const int c0 = c * LCHUNK;
  const int Leff = min(LCHUNK, nf - c0);
  if (Leff <= 0) return;

  const uint4* __restrict__ sch = sched + c0;   // block-uniform -> s_load
  const uint32_t base = 8u * (uint32_t)t;       // 2 * n0
  float4* o = (float4*)(out + (size_t)c0 * N + n0);
  const int ostr = N >> 2;   // float4 stride per frame

  uint32_t sA[4], sB[4], mf[4] = {0u, 0u, 0u, 0u};
  int f = 0;

  if (c == 0) {
    const float4 iv0 = ((const float4*)initial)[2 * t];      // particles n0, n0+1
    const float4 iv1 = ((const float4*)initial)[2 * t + 1];  // particles n0+2, n0+3
    sA[0] = (iv0.x < 0.5f) ? 1u : 0u;
    sA[1] = (iv0.z < 0.5f) ? 1u : 0u;
    sA[2] = (iv1.x < 0.5f) ? 1u : 0u;
    sA[3] = (iv1.z < 0.5f) ? 1u : 0u;
#pragma unroll
    for (int i = 0; i < 4; ++i) sB[i] = sA[i];
  } else {
#pragma unroll
    for (int i = 0; i < 4; ++i) { sA[i] = 0u; sB[i] = 1u; }
    // Warmup + couple phase: both chains for all particles (no per-lane
    // branch; merged lanes compute identical updates). Exit is wave-uniform:
    // break only when EVERY lane's four particles have all coupled.
    uint32_t d = 1u;
    for (; f < Leff; ++f) {
      if (f >= F0 && !__any((int)d)) break;
      const uint4 sc = sch[f];
      d = 0u;
#pragma unroll
      for (int i = 0; i < 4; ++i) {
        const uint32_t di =
            bothstep(sc.x, sc.y, sc.z, base + 2u * i, sA[i], sB[i]);
        mf[i] += di; d |= di;
      }
      *o = make_float4(sA[0] ? 0.0f : 1.0f, sA[1] ? 0.0f : 1.0f,
                       sA[2] ? 0.0f : 1.0f, sA[3] ? 0.0f : 1.0f);
      o += ostr;
    }
  }
  const int fm = f;  // frame index at merged-loop entry
  // Merged steady state: one threefry per particle per frame, ILP-4.
  // Schedule value for frame f+1 is prefetched to break the s_load->use chain
  // (table is padded by one entry so sch[f+1] is always in bounds).
  uint4 sc = sch[f < Leff ? f : Leff - 1];
  for (; f < Leff; ++f) {
    const uint4 scn = sch[f + 1];
#pragma unroll
    for (int i = 0; i < 4; ++i) mstep(sc.x, sc.y, sc.z, base + 2u * i, sA[i]);
    *o = make_float4(sA[0] ? 0.0f : 1.0f, sA[1] ? 0.0f : 1.0f,
                     sA[2] ? 0.0f : 1.0f, sA[3] ? 0.0f : 1.0f);
    o += ostr;
    sc = scn;
  }
  // If the merged loop ran (c==0 always; c>0 only after the wave-uniform
  // break, which requires ALL particles coupled), chain B tracks chain A.
  // If the couple phase ran the whole chunk, keep the live sB values.
  if (fm < Leff) {
#pragma unroll
    for (int i = 0; i < 4; ++i) sB[i] = sA[i];
  }
  // Per particle: final(entry=0) | final(entry=1)<<1 | pre-merge count<<2.
  uchar4 w;
  w.x = (uint8_t)(sA[0] | (sB[0] << 1) | (mf[0] << 2));
  w.y = (uint8_t)(sA[1] | (sB[1] << 1) | (mf[1] << 2));
  w.z = (uint8_t)(sA[2] | (sB[2] << 1) | (mf[2] << 2));
  w.w = (uint8_t)(sA[3] | (sB[3] << 1) | (mf[3] << 2));
  fin[(size_t)c * (N >> 2) + t] = w;
}

// Kernel 2: per particle, compose chunk finals; where the true entry state
// of a speculative chunk was 1, flip the pre-merge output rows (chain B's
// pre-merge outputs are exactly 1 - chain A's).
__global__ __launch_bounds__(256) void hmm_fix(
    const float* __restrict__ initial,
    float* __restrict__ out,
    const uint8_t* __restrict__ fin,
    int N, int C) {
  const int n = blockIdx.x * blockDim.x + threadIdx.x;
  if (n >= N) return;
  uint32_t s = (initial[2 * n] < 0.5f) ? 1u : 0u;
  for (int c = 0; c < C; ++c) {
    const uint32_t w = fin[(size_t)c * N + n];
    if (c > 0 && s == 1u) {
      const int c0 = c * LCHUNK;
      const int mf = (int)(w >> 2);
      for (int f = 0; f < mf; ++f) {
        float* q = out + (size_t)(c0 + f) * N + n;
        *q = 1.0f - *q;
      }
    }
    s = (s == 0u) ? (w & 1u) : ((w >> 1) & 1u);
  }
}

extern "C" void kernel_launch(void* const* d_in, const int* in_sizes, int n_in,
                              void* d_out, int out_size, void* d_ws, size_t ws_size,
                              hipStream_t stream) {
  const float* initial = (const float*)d_in[0];
  // d_in[1] = transition_matrix: constant identity/swap, folded into bit-flip
  const float* initial_trans = (const float*)d_in[2];
  float* out = (float*)d_out;

  const int N = in_sizes[0] / 2;          // 100000
  const int nf = out_size / N;            // 500
  const int C = (nf + LCHUNK - 1) / LCHUNK;

  uint4* sched = (uint4*)d_ws;
  const size_t finoff = (((size_t)(nf + 1) * 16) + 511) & ~(size_t)511;
  uint8_t* fin = (uint8_t*)d_ws + finoff;

  hipLaunchKernelGGL(hmm_sched, dim3((nf + 1 + 255) / 256), dim3(256), 0, stream,
                     initial_trans, sched, nf);
  const int gx = (N / 4 + 255) / 256;
  hipLaunchKernelGGL(hmm_main, dim3(gx, C), dim3(256), 0, stream,
                     initial, sched, out, (uchar4*)fin, N, nf);
  hipLaunchKernelGGL(hmm_fix, dim3((N + 255) / 256), dim3(256), 0, stream,
                     initial, out, fin, N, C);
}

// Round 6
// 132.855 us; speedup vs baseline: 1.1916x; 1.1916x over previous
//
#include <hip/hip_runtime.h>
#include <stdint.h>

// Threefry-2x32, 20 rounds (Random123 / JAX threefry2x32_p).
__device__ __forceinline__ void tf2x32(uint32_t k0, uint32_t k1,
                                       uint32_t x0, uint32_t x1,
                                       uint32_t& o0, uint32_t& o1) {
  const uint32_t ks2 = k0 ^ k1 ^ 0x1BD11BDAu;
  x0 += k0; x1 += k1;
#define TF_R(r) { x0 += x1; x1 = __builtin_rotateleft32(x1, (r)); x1 ^= x0; }
  TF_R(13) TF_R(15) TF_R(26) TF_R(6)
  x0 += k1; x1 += ks2 + 1u;
  TF_R(17) TF_R(29) TF_R(16) TF_R(24)
  x0 += ks2; x1 += k0 + 2u;
  TF_R(13) TF_R(15) TF_R(26) TF_R(6)
  x0 += k0; x1 += k1 + 3u;
  TF_R(17) TF_R(29) TF_R(16) TF_R(24)
  x0 += k1; x1 += ks2 + 4u;
  TF_R(13) TF_R(15) TF_R(26) TF_R(6)
  x0 += ks2; x1 += k0 + 5u;
#undef TF_R
  o0 = x0; o1 = x1;
}

#define F0 8   // unconditional both-chain warmup frames

// Work-balanced chunk boundaries: spec chunks pay ~10 double-work couple
// frames, so chunk 0 gets L+10 frames and spec chunks get L.
//   L = (nf - 10) / C ; CH0 = nf - (C-1)*L
// nf=500, C=5 -> CH0=108, L=98 (each chunk ~108 frame-equivalents).
__device__ __forceinline__ void chunk_geom(int nf, int C, int c,
                                           int& c0, int& len) {
  const int L = (nf - 10) / C;
  const int CH0 = nf - (C - 1) * L;
  c0 = (c == 0) ? 0 : CH0 + (c - 1) * L;
  len = (c == 0) ? CH0 : min(L, nf - c0);
}

// Kernel 0: per-frame schedule {ku0, ku1, thr32} -> uint4 table in ws.
// Writes nf+1 entries (entry nf pads the main loop's prefetch).
// thr32 = ceil(p * 2^23) << 9 so that (uniform(u) < p) == (bits < thr32).
__global__ __launch_bounds__(256) void hmm_sched(
    const float* __restrict__ initial_trans,
    uint4* __restrict__ sched, int nf) {
  const int gi = blockIdx.x * blockDim.x + threadIdx.x;
  if (gi > nf) return;
  const float trans = initial_trans[0];
  uint32_t f0_, f1_, t0, t1;
  tf2x32(0u, 42u, 0u, (uint32_t)gi, f0_, f1_);        // fold_in(key(42), gi)
  tf2x32(f0_, f1_, 0u, 0u, t0, t1);                   // ku = split[0]
  const int jf = gi - (gi % 100);                     // p refresh anchor
  uint32_t g0, g1, kr0, kr1, a0, a1, b0, b1, h0, h1, l0, l1;
  tf2x32(0u, 42u, 0u, (uint32_t)jf, g0, g1);
  tf2x32(g0, g1, 0u, 1u, kr0, kr1);                   // kr = split[1]
  tf2x32(kr0, kr1, 0u, 0u, a0, a1);                   // randint: k1
  tf2x32(kr0, kr1, 0u, 1u, b0, b1);                   //          k2
  tf2x32(a0, a1, 0u, 0u, h0, h1);
  tf2x32(b0, b1, 0u, 0u, l0, l1);
  const uint32_t hb = h0 ^ h1, lb = l0 ^ l1;
  const uint32_t off = ((hb % 9u) * 4u + (lb % 9u)) % 9u;  // span 9, mult 4
  const float p = trans * (float)(1u + off);
  const uint32_t mant = (uint32_t)ceilf(p * 8388608.0f);
  sched[gi] = make_uint4(t0, t1, mant << 9, 0u);
}

// Both-chain update for one particle; returns 1 if chains still differ.
__device__ __forceinline__ uint32_t bothstep(uint32_t k0, uint32_t k1,
                                             uint32_t tp, uint32_t twon,
                                             uint32_t& sA, uint32_t& sB) {
  uint32_t a0, a1, b0, b1;
  tf2x32(k0, k1, 0u, twon, a0, a1);          // element for state 0
  tf2x32(k0, k1, 0u, twon + 1u, b0, b1);     // element for state 1
  const uint32_t flip0 = ((a0 ^ a1) < 0x80000000u) ? 1u : 0u;
  const uint32_t flip1 = ((b0 ^ b1) < tp) ? 1u : 0u;
  sA = sA ? (1u ^ flip1) : flip0;
  sB = sB ? (1u ^ flip1) : flip0;
  return (sA != sB) ? 1u : 0u;
}

// Merged single-chain update.
__device__ __forceinline__ void mstep(uint32_t k0, uint32_t k1, uint32_t tp,
                                      uint32_t twon, uint32_t& s) {
  uint32_t a0, a1;
  tf2x32(k0, k1, 0u, twon + s, a0, a1);
  const uint32_t thr = s ? tp : 0x80000000u;
  s ^= ((a0 ^ a1) < thr) ? 1u : 0u;
}

// Kernel 1: each thread owns TWO particles (2t, 2t+1) for one frame chunk.
// chunk 0 runs the true chain; chunks c>0 run both entry states until the
// chains couple (merge), then a single merged chain. Chunks are interleaved
// across blockIdx (c = bid % C) so every CU sees the same work mix.
__global__ __launch_bounds__(256) void hmm_main(
    const float* __restrict__ initial,
    const uint4* __restrict__ sched,
    float* __restrict__ out,
    uint32_t* __restrict__ fin,
    int N, int nf, int C) {
  const int c = blockIdx.x % C;
  const int tb = blockIdx.x / C;
  const int t = tb * blockDim.x + threadIdx.x;
  const int n0 = 2 * t;
  if (n0 >= N) return;
  int c0, Leff;
  chunk_geom(nf, C, c, c0, Leff);
  if (Leff <= 0) return;

  const uint4* __restrict__ sch = sched + c0;   // block-uniform -> s_load
  const uint32_t twon0 = 2u * (uint32_t)n0;
  const uint32_t twon1 = twon0 + 2u;
  float2* o = (float2*)(out + (size_t)c0 * N + n0);
  const int ostr = N >> 1;   // float2 stride per frame

  uint32_t s0A, s0B, s1A, s1B, mf0 = 0, mf1 = 0;
  int f = 0;

  if (c == 0) {
    const float4 iv = *(const float4*)(initial + 2 * n0);  // [p0s0,p0s1,p1s0,p1s1]
    s0A = (iv.x < 0.5f) ? 1u : 0u;  s0B = s0A;
    s1A = (iv.z < 0.5f) ? 1u : 0u;  s1B = s1A;
  } else {
    s0A = 0u; s0B = 1u; s1A = 0u; s1B = 1u;
    // Warmup + couple phase: both chains for both particles (no per-lane
    // branch; merged lanes compute identical updates). Exit is wave-uniform:
    // break only when EVERY lane's particles have coupled (sA==sB).
    uint32_t d = 1u;
    for (; f < Leff; ++f) {
      if (f >= F0 && !__any((int)d)) break;
      const uint4 sc = sch[f];
      const uint32_t d0 = bothstep(sc.x, sc.y, sc.z, twon0, s0A, s0B);
      const uint32_t d1 = bothstep(sc.x, sc.y, sc.z, twon1, s1A, s1B);
      mf0 += d0; mf1 += d1; d = d0 | d1;
      *o = make_float2(s0A ? 0.0f : 1.0f, s1A ? 0.0f : 1.0f);
      o += ostr;
    }
  }
  const int fm = f;  // frame index at merged-loop entry
  // Merged steady state: one threefry per particle per frame. Schedule for
  // frame f+1 is prefetched to break the s_load->use chain (table padded).
  uint4 sc = sch[f < Leff ? f : Leff - 1];
  for (; f < Leff; ++f) {
    const uint4 scn = sch[f + 1];
    mstep(sc.x, sc.y, sc.z, twon0, s0A);
    mstep(sc.x, sc.y, sc.z, twon1, s1A);
    *o = make_float2(s0A ? 0.0f : 1.0f, s1A ? 0.0f : 1.0f);
    o += ostr;
    sc = scn;
  }
  // If the merged loop ran (c==0 always; c>0 only after the wave-uniform
  // break, which requires ALL particles coupled), chain B tracks chain A.
  // If the couple phase ran the whole chunk, keep the live sB values.
  if (fm < Leff) { s0B = s0A; s1B = s1A; }
  // finals for both entry states + count of pre-merge (differing) frames
  *(uint2*)(fin + (size_t)c * N + n0) =
      make_uint2(s0A | (s0B << 1) | (mf0 << 2), s1A | (s1B << 1) | (mf1 << 2));
}

// Kernel 2: per particle, compose chunk finals; where the true entry state
// of a speculative chunk was 1, flip the pre-merge output rows (chain B's
// pre-merge outputs are exactly 1 - chain A's).
__global__ __launch_bounds__(256) void hmm_fix(
    const float* __restrict__ initial,
    float* __restrict__ out,
    const uint32_t* __restrict__ fin,
    int N, int nf, int C) {
  const int n = blockIdx.x * blockDim.x + threadIdx.x;
  if (n >= N) return;
  uint32_t s = (initial[2 * n] < 0.5f) ? 1u : 0u;
  for (int c = 0; c < C; ++c) {
    const uint32_t w = fin[(size_t)c * N + n];
    if (c > 0 && s == 1u) {
      int c0, len;
      chunk_geom(nf, C, c, c0, len);
      const int mf = (int)(w >> 2);
      for (int f = 0; f < mf; ++f) {
        float* q = out + (size_t)(c0 + f) * N + n;
        *q = 1.0f - *q;
      }
    }
    s = (s == 0u) ? (w & 1u) : ((w >> 1) & 1u);
  }
}

extern "C" void kernel_launch(void* const* d_in, const int* in_sizes, int n_in,
                              void* d_out, int out_size, void* d_ws, size_t ws_size,
                              hipStream_t stream) {
  const float* initial = (const float*)d_in[0];
  // d_in[1] = transition_matrix: constant identity/swap, folded into bit-flip
  const float* initial_trans = (const float*)d_in[2];
  float* out = (float*)d_out;

  const int N = in_sizes[0] / 2;          // 100000
  const int nf = out_size / N;            // 500
  const int C = max(1, (nf + 99) / 100);  // 5

  uint4* sched = (uint4*)d_ws;
  const size_t finoff = (((size_t)(nf + 1) * 16) + 511) & ~(size_t)511;
  uint32_t* fin = (uint32_t*)((char*)d_ws + finoff);

  hipLaunchKernelGGL(hmm_sched, dim3((nf + 1 + 255) / 256), dim3(256), 0, stream,
                     initial_trans, sched, nf);
  const int gx = (N / 2 + 255) / 256;
  hipLaunchKernelGGL(hmm_main, dim3(gx * C), dim3(256), 0, stream,
                     initial, sched, out, fin, N, nf, C);
  hipLaunchKernelGGL(hmm_fix, dim3((N + 255) / 256), dim3(256), 0, stream,
                     initial, out, fin, N, nf, C);
}

// Round 7
// 131.518 us; speedup vs baseline: 1.2037x; 1.0102x over previous
//
#include <hip/hip_runtime.h>
#include <stdint.h>

// Threefry-2x32, 20 rounds (Random123 / JAX threefry2x32_p).
__device__ __forceinline__ void tf2x32(uint32_t k0, uint32_t k1,
                                       uint32_t x0, uint32_t x1,
                                       uint32_t& o0, uint32_t& o1) {
  const uint32_t ks2 = k0 ^ k1 ^ 0x1BD11BDAu;
  x0 += k0; x1 += k1;
#define TF_R(r) { x0 += x1; x1 = __builtin_rotateleft32(x1, (r)); x1 ^= x0; }
  TF_R(13) TF_R(15) TF_R(26) TF_R(6)
  x0 += k1; x1 += ks2 + 1u;
  TF_R(17) TF_R(29) TF_R(16) TF_R(24)
  x0 += ks2; x1 += k0 + 2u;
  TF_R(13) TF_R(15) TF_R(26) TF_R(6)
  x0 += k0; x1 += k1 + 3u;
  TF_R(17) TF_R(29) TF_R(16) TF_R(24)
  x0 += k1; x1 += ks2 + 4u;
  TF_R(13) TF_R(15) TF_R(26) TF_R(6)
  x0 += ks2; x1 += k0 + 5u;
#undef TF_R
  o0 = x0; o1 = x1;
}

#define F0 8   // unconditional both-chain warmup frames

// Work-balanced chunk boundaries: spec chunks pay ~11 double-work couple
// frames, so chunk 0 gets L+10 frames and spec chunks get L.
__device__ __forceinline__ void chunk_geom(int nf, int C, int c,
                                           int& c0, int& len) {
  const int L = (nf - 10) / C;
  const int CH0 = nf - (C - 1) * L;
  c0 = (c == 0) ? 0 : CH0 + (c - 1) * L;
  len = (c == 0) ? CH0 : min(L, nf - c0);
}

// Kernel 0: per-frame schedule {ku0, ku1, thr32} -> uint4 table in ws.
// Writes nf+3 entries (pads for the main loop's 2-deep prefetch).
// thr32 = ceil(p * 2^23) << 9 so that (uniform(u) < p) == (bits < thr32).
__global__ __launch_bounds__(256) void hmm_sched(
    const float* __restrict__ initial_trans,
    uint4* __restrict__ sched, int nf) {
  const int gi = blockIdx.x * blockDim.x + threadIdx.x;
  if (gi > nf + 2) return;
  const float trans = initial_trans[0];
  uint32_t f0_, f1_, t0, t1;
  tf2x32(0u, 42u, 0u, (uint32_t)gi, f0_, f1_);        // fold_in(key(42), gi)
  tf2x32(f0_, f1_, 0u, 0u, t0, t1);                   // ku = split[0]
  const int jf = gi - (gi % 100);                     // p refresh anchor
  uint32_t g0, g1, kr0, kr1, a0, a1, b0, b1, h0, h1, l0, l1;
  tf2x32(0u, 42u, 0u, (uint32_t)jf, g0, g1);
  tf2x32(g0, g1, 0u, 1u, kr0, kr1);                   // kr = split[1]
  tf2x32(kr0, kr1, 0u, 0u, a0, a1);                   // randint: k1
  tf2x32(kr0, kr1, 0u, 1u, b0, b1);                   //          k2
  tf2x32(a0, a1, 0u, 0u, h0, h1);
  tf2x32(b0, b1, 0u, 0u, l0, l1);
  const uint32_t hb = h0 ^ h1, lb = l0 ^ l1;
  const uint32_t off = ((hb % 9u) * 4u + (lb % 9u)) % 9u;  // span 9, mult 4
  const float p = trans * (float)(1u + off);
  const uint32_t mant = (uint32_t)ceilf(p * 8388608.0f);
  sched[gi] = make_uint4(t0, t1, mant << 9, 0u);
}

// Both-chain update for one particle; returns 1 if chains still differ.
__device__ __forceinline__ uint32_t bothstep(uint32_t k0, uint32_t k1,
                                             uint32_t tp, uint32_t twon,
                                             uint32_t& sA, uint32_t& sB) {
  uint32_t a0, a1, b0, b1;
  tf2x32(k0, k1, 0u, twon, a0, a1);          // element for state 0
  tf2x32(k0, k1, 0u, twon + 1u, b0, b1);     // element for state 1
  const uint32_t flip0 = ((a0 ^ a1) < 0x80000000u) ? 1u : 0u;
  const uint32_t flip1 = ((b0 ^ b1) < tp) ? 1u : 0u;
  sA = sA ? (1u ^ flip1) : flip0;
  sB = sB ? (1u ^ flip1) : flip0;
  return (sA != sB) ? 1u : 0u;
}

// Merged single-chain update.
__device__ __forceinline__ void mstep(uint32_t k0, uint32_t k1, uint32_t tp,
                                      uint32_t twon, uint32_t& s) {
  uint32_t a0, a1;
  tf2x32(k0, k1, 0u, twon + s, a0, a1);
  const uint32_t thr = s ? tp : 0x80000000u;
  s ^= ((a0 ^ a1) < thr) ? 1u : 0u;
}

// Kernel 1: each thread owns TWO particles (2t, 2t+1) for one frame chunk.
// chunk 0 runs the true chain; chunks c>0 run both entry states until the
// chains couple (merge), then a single merged chain. Chunks are interleaved
// across blockIdx (c = bid % C) so every CU sees the same work mix.
__global__ __launch_bounds__(256) void hmm_main(
    const float* __restrict__ initial,
    const uint4* __restrict__ sched,
    float* __restrict__ out,
    uint32_t* __restrict__ fin,
    int N, int nf, int C) {
  const int c = blockIdx.x % C;
  const int tb = blockIdx.x / C;
  const int t = tb * blockDim.x + threadIdx.x;
  const int n0 = 2 * t;
  if (n0 >= N) return;
  int c0, Leff;
  chunk_geom(nf, C, c, c0, Leff);
  if (Leff <= 0) return;

  const uint4* __restrict__ sch = sched + c0;   // block-uniform -> s_load
  const uint32_t twon0 = 2u * (uint32_t)n0;
  const uint32_t twon1 = twon0 + 2u;
  float2* o = (float2*)(out + (size_t)c0 * N + n0);
  const int ostr = N >> 1;   // float2 stride per frame

  uint32_t s0A, s0B, s1A, s1B, mf0 = 0, mf1 = 0;
  int f = 0;

  if (c == 0) {
    const float4 iv = *(const float4*)(initial + 2 * n0);  // [p0s0,p0s1,p1s0,p1s1]
    s0A = (iv.x < 0.5f) ? 1u : 0u;  s0B = s0A;
    s1A = (iv.z < 0.5f) ? 1u : 0u;  s1B = s1A;
  } else {
    s0A = 0u; s0B = 1u; s1A = 0u; s1B = 1u;
    // Warmup + couple phase: both chains for both particles (no per-lane
    // branch; merged lanes compute identical updates). Exit is wave-uniform:
    // break only when EVERY lane's particles have coupled (sA==sB).
    uint32_t d = 1u;
    for (; f < Leff; ++f) {
      if (f >= F0 && !__any((int)d)) break;
      const uint4 sc = sch[f];
      const uint32_t d0 = bothstep(sc.x, sc.y, sc.z, twon0, s0A, s0B);
      const uint32_t d1 = bothstep(sc.x, sc.y, sc.z, twon1, s1A, s1B);
      mf0 += d0; mf1 += d1; d = d0 | d1;
      *o = make_float2(s0A ? 0.0f : 1.0f, s1A ? 0.0f : 1.0f);
      o += ostr;
    }
  }
  const int fm = f;  // frame index at merged-loop entry
  // Merged steady state: one threefry per particle per frame, unrolled x2
  // with a 2-deep schedule prefetch (table padded by 3 entries, so all
  // prefetch reads are in bounds even at f == Leff).
  uint4 sc0 = sch[f];
  uint4 sc1 = sch[f + 1];
  for (; f + 2 <= Leff; f += 2) {
    const uint4 sc2 = sch[f + 2];
    const uint4 sc3 = sch[f + 3];
    mstep(sc0.x, sc0.y, sc0.z, twon0, s0A);
    mstep(sc0.x, sc0.y, sc0.z, twon1, s1A);
    o[0] = make_float2(s0A ? 0.0f : 1.0f, s1A ? 0.0f : 1.0f);
    mstep(sc1.x, sc1.y, sc1.z, twon0, s0A);
    mstep(sc1.x, sc1.y, sc1.z, twon1, s1A);
    o[ostr] = make_float2(s0A ? 0.0f : 1.0f, s1A ? 0.0f : 1.0f);
    o += 2 * ostr;
    sc0 = sc2; sc1 = sc3;
  }
  if (f < Leff) {
    mstep(sc0.x, sc0.y, sc0.z, twon0, s0A);
    mstep(sc0.x, sc0.y, sc0.z, twon1, s1A);
    *o = make_float2(s0A ? 0.0f : 1.0f, s1A ? 0.0f : 1.0f);
    ++f;
  }
  // If the merged loop ran (c==0 always; c>0 only after the wave-uniform
  // break, which requires ALL particles coupled), chain B tracks chain A.
  // If the couple phase ran the whole chunk, keep the live sB values.
  if (fm < Leff) { s0B = s0A; s1B = s1A; }
  // finals for both entry states + count of pre-merge (differing) frames
  *(uint2*)(fin + (size_t)c * N + n0) =
      make_uint2(s0A | (s0B << 1) | (mf0 << 2), s1A | (s1B << 1) | (mf1 << 2));
}

// Kernel 2: per particle, compose chunk finals; where the true entry state
// of a speculative chunk was 1, flip the pre-merge output rows (chain B's
// pre-merge outputs are exactly 1 - chain A's).
__global__ __launch_bounds__(256) void hmm_fix(
    const float* __restrict__ initial,
    float* __restrict__ out,
    const uint32_t* __restrict__ fin,
    int N, int nf, int C) {
  const int n = blockIdx.x * blockDim.x + threadIdx.x;
  if (n >= N) return;
  uint32_t s = (initial[2 * n] < 0.5f) ? 1u : 0u;
  for (int c = 0; c < C; ++c) {
    const uint32_t w = fin[(size_t)c * N + n];
    if (c > 0 && s == 1u) {
      int c0, len;
      chunk_geom(nf, C, c, c0, len);
      const int mf = (int)(w >> 2);
      for (int f = 0; f < mf; ++f) {
        float* q = out + (size_t)(c0 + f) * N + n;
        *q = 1.0f - *q;
      }
    }
    s = (s == 0u) ? (w & 1u) : ((w >> 1) & 1u);
  }
}

extern "C" void kernel_launch(void* const* d_in, const int* in_sizes, int n_in,
                              void* d_out, int out_size, void* d_ws, size_t ws_size,
                              hipStream_t stream) {
  const float* initial = (const float*)d_in[0];
  // d_in[1] = transition_matrix: constant identity/swap, folded into bit-flip
  const float* initial_trans = (const float*)d_in[2];
  float* out = (float*)d_out;

  const int N = in_sizes[0] / 2;          // 100000
  const int nf = out_size / N;            // 500
  const int C = max(1, (nf + 99) / 100);  // 5

  uint4* sched = (uint4*)d_ws;
  const size_t finoff = (((size_t)(nf + 3) * 16) + 511) & ~(size_t)511;
  uint32_t* fin = (uint32_t*)((char*)d_ws + finoff);

  hipLaunchKernelGGL(hmm_sched, dim3((nf + 3 + 255) / 256), dim3(256), 0, stream,
                     initial_trans, sched, nf);
  const int gx = (N / 2 + 255) / 256;
  hipLaunchKernelGGL(hmm_main, dim3(gx * C), dim3(256), 0, stream,
                     initial, sched, out, fin, N, nf, C);
  hipLaunchKernelGGL(hmm_fix, dim3((N + 255) / 256), dim3(256), 0, stream,
                     initial, out, fin, N, nf, C);
}